// Round 1
// 56.561 us; speedup vs baseline: 1.0152x; 1.0152x over previous
//
#include <hip/hip_runtime.h>

// SoftRank via per-column counting-sort + windowed exact sigmoid.
// out[b,j,c] = (1/N) * sum_i sigmoid(1000*(x[b,j,c]-x[b,i,c]))
// With ALPHA=1000, terms saturate outside |dx| ~ 0.012. Per (b,c) column:
//   1) bucket-sort the 1024 values (1024 buckets over [-6,6))
//   2) out[j] = ( #{i in buckets <= k-2} + sum_{i in buckets k-1..k+1} sigmoid )/N
// Bucket width in log2-units = 12*K/NB = 16.9 -> omitted-term error 2^-16.9 each.
//
// v2: replace the 20-barrier Hillis-Steele scan with a hierarchical scan:
//   wave-level __shfl_up inclusive scan (no barriers) + 16-entry cross-wave
//   scan by wave 0. Barriers per block: 22 -> 6. The kernel is latency-bound
//   on the per-block serial chain (HBM ~1MB, trans ~3.4M are both negligible),
//   so cutting barrier count is the lever.

#define K_LOG2E 1442.6950408889634f  // 1000 * log2(e)

constexpr int Bdim = 8;
constexpr int Ndim = 1024;
constexpr int Cdim = 16;
constexpr int NB   = 1024;          // buckets (== blockDim for easy init/scan)
constexpr float RANGE = 6.0f;       // bucket domain [-6, 6) in raw units

__global__ __launch_bounds__(1024)
void softrank_bucket(const float* __restrict__ x, float* __restrict__ out) {
    __shared__ int   cnt[NB];    // histogram
    __shared__ int   cum[NB];    // inclusive prefix
    __shared__ int   off[NB];    // scatter cursors (exclusive prefix)
    __shared__ float sv[Ndim];   // bucket-ordered scaled values
    __shared__ int   wsum[16];   // per-wave totals for hierarchical scan

    const int t    = threadIdx.x;       // element index i in the column
    const int lane = t & 63;
    const int w    = t >> 6;            // wave id, 0..15
    const int b    = blockIdx.x >> 4;
    const int c    = blockIdx.x & 15;

    // Load my element (scaled to log2-sigmoid units).
    const float v = K_LOG2E * x[b * (Ndim * Cdim) + t * Cdim + c];

    // Bucket index.
    const float inv_w = (float)NB / (2.0f * RANGE * K_LOG2E);
    int k = (int)floorf((v + RANGE * K_LOG2E) * inv_w);
    k = min(max(k, 0), NB - 1);

    // Histogram.
    cnt[t] = 0;
    __syncthreads();                    // B1
    atomicAdd(&cnt[k], 1);
    __syncthreads();                    // B2

    // Hierarchical inclusive prefix sum over buckets.
    const int myc = cnt[t];
    int s = myc;
    #pragma unroll
    for (int d = 1; d < 64; d <<= 1) {  // wave-level scan, no barriers
        int n = __shfl_up(s, d, 64);
        if (lane >= d) s += n;
    }
    if (lane == 63) wsum[w] = s;
    __syncthreads();                    // B3
    if (w == 0) {                       // scan the 16 wave totals
        int ws = (lane < 16) ? wsum[lane] : 0;
        #pragma unroll
        for (int d = 1; d < 16; d <<= 1) {
            int n = __shfl_up(ws, d, 64);
            if (lane >= d) ws += n;
        }
        if (lane < 16) wsum[lane] = ws; // inclusive wave prefix
    }
    __syncthreads();                    // B4
    const int inc = ((w > 0) ? wsum[w - 1] : 0) + s;  // global inclusive prefix
    cum[t] = inc;
    off[t] = inc - myc;                 // exclusive prefix = scatter cursor
    __syncthreads();                    // B5

    // Scatter into bucket order.
    int pos = atomicAdd(&off[k], 1);
    sv[pos] = v;
    __syncthreads();                    // B6

    // Window = buckets [k-1, k+1]; everything in buckets <= k-2 contributes ~1
    // (scaled distance > 16.9 log2-units, deficit 2^-16.9 per term).
    const int lo = (k >= 2) ? cum[k - 2] : 0;             // excl prefix of bucket k-1
    const int hi = (k + 1 <= NB - 1) ? cum[k + 1] : Ndim; // incl prefix of bucket k+1

    float acc = 0.0f;
    for (int p = lo; p < hi; ++p) {
        float u = v - sv[p];                         // log2-units
        float e = __builtin_amdgcn_exp2f(-u);        // exp(-alpha*dx)
        acc += __builtin_amdgcn_rcpf(1.0f + e);      // sigmoid
    }

    out[b * (Ndim * Cdim) + t * Cdim + c] = ((float)lo + acc) * (1.0f / (float)Ndim);
}

extern "C" void kernel_launch(void* const* d_in, const int* in_sizes, int n_in,
                              void* d_out, int out_size, void* d_ws, size_t ws_size,
                              hipStream_t stream) {
    (void)in_sizes; (void)n_in; (void)d_ws; (void)ws_size; (void)out_size;
    const float* x = (const float*)d_in[0];
    float* out = (float*)d_out;
    softrank_bucket<<<Bdim * Cdim, 1024, 0, stream>>>(x, out);
}